// Round 6
// baseline (825.091 us; speedup 1.0000x reference)
//
#include <hip/hip_runtime.h>
#include <hip/hip_bf16.h>

// InteractionBlock: B=16,N=192,H=128,F=128,G=50
//   fw  = softplus(rbf@W1+b1)@W2+b2          [B,N,N,F]   (never materialized)
//   nf  = features@Wf+bf                      [B,N,F]
//   agg = sum_j mask[b,i,j]*fw[b,i,j,:]*nf[b,j,:]
//   out = features + softplus(agg@Wo1+bo1)@Wo2+bo2
//
// v7 = v5 loop structure + v6 register discipline + A-prefetch.
//  - v6 post-mortem: MFMA-busy 11.8us, VALU-busy ~70us, idle ~170us. 9216
//    blocks paid 3x per-block ramp; phase-aligned waves never mixed pipes.
//    v1 (178us @ 22% occ) beat v6 (250us @ 43%) on amortization alone.
//  - 3072 blocks; wave loops 3 thirds. #pragma unroll 1 + sched_barrier(0)
//    at loop head forbid the cross-iteration scheduling that blew v5 up to
//    164 VGPR; __launch_bounds__(256,4) caps at 128 -> 4 waves/SIMD.
//  - 1-deep prefetch of next third's A-fragment issued after GEMM1 ->
//    global latency hides under softplus+GEMM2.
//  - Direct agg store (s_red reduction), no atomics; prep doesn't zero agg.
//  - All math paths v5/v6-verbatim (twice harness-proven).

typedef __bf16 bf16_t;
typedef __bf16 bf16x8 __attribute__((ext_vector_type(8)));
typedef float  f32x4  __attribute__((ext_vector_type(4)));
typedef unsigned int uintx4 __attribute__((ext_vector_type(4)));

constexpr int kB = 16, kN = 192, kH = 128, kF = 128, kG = 50;
constexpr int kRows = kB * kN;        // 3072
constexpr int kOutPitch = 136;        // bf16 elems, mult of 8 -> aligned b128

__device__ __forceinline__ float ldf(const void* p, int i, bool bfm) {
  return bfm ? (float)((const bf16_t*)p)[i] : ((const float*)p)[i];
}

__device__ __forceinline__ float softplus_f(float x) {
  float t = __logf(1.f + __expf(fminf(x, 20.f)));
  return x > 20.f ? x : t;
}

// ---- dtype detector: flag=1 if inputs are packed bf16, 0 if fp32 ----
__global__ __launch_bounds__(256) void detect_kernel(const unsigned int* __restrict__ rbf_w,
                                                     int* __restrict__ flag) {
  __shared__ int c_hi, c_zero;
  const int t = threadIdx.x;
  if (t == 0) { c_hi = 0; c_zero = 0; }
  __syncthreads();
  unsigned int w = rbf_w[(size_t)t * 40003u];   // in-bounds for both dtypes
  unsigned int lo = w & 0xFFFFu;
  if (((lo >> 7) & 0xFFu) >= 128u) atomicAdd(&c_hi, 1);   // |bf16| >= 2: impossible for rbf in [0,1)
  if (lo == 0u) atomicAdd(&c_zero, 1);
  __syncthreads();
  if (t == 0) *flag = (c_hi == 0 && c_zero < 200) ? 1 : 0;
}

// ---- transpose all weight matrices into bf16 [n][k] ----
__global__ __launch_bounds__(256) void prep_kernel(
    const void* __restrict__ W1, const void* __restrict__ W2,
    const void* __restrict__ Wf, const void* __restrict__ Wo1,
    const void* __restrict__ Wo2, const int* __restrict__ flag,
    bf16_t* __restrict__ w1t, bf16_t* __restrict__ w2t,
    bf16_t* __restrict__ wft, bf16_t* __restrict__ wo1t,
    bf16_t* __restrict__ wo2t) {
  const bool bfm = *flag != 0;
  int idx = blockIdx.x * 256 + threadIdx.x;
  if (idx < 8192) {                       // w1t [128][64], G padded 50->64 with zeros
    int n = idx >> 6, k = idx & 63;
    w1t[idx] = (k < kG) ? (bf16_t)ldf(W1, k * kF + n, bfm) : (bf16_t)0.f;
  } else if (idx < 8192 + 16384) {        // w2t [128][128]
    int i2 = idx - 8192; int n = i2 >> 7, k = i2 & 127;
    w2t[i2] = (bf16_t)ldf(W2, k * kF + n, bfm);
  } else if (idx < 8192 + 2 * 16384) {    // wft
    int i2 = idx - 8192 - 16384; int n = i2 >> 7, k = i2 & 127;
    wft[i2] = (bf16_t)ldf(Wf, k * kF + n, bfm);
  } else if (idx < 8192 + 3 * 16384) {    // wo1t
    int i2 = idx - 8192 - 2 * 16384; int n = i2 >> 7, k = i2 & 127;
    wo1t[i2] = (bf16_t)ldf(Wo1, k * kH + n, bfm);
  } else if (idx < 8192 + 4 * 16384) {    // wo2t
    int i2 = idx - 8192 - 3 * 16384; int n = i2 >> 7, k = i2 & 127;
    wo2t[i2] = (bf16_t)ldf(Wo2, k * kH + n, bfm);
  }
}

// ---- nf = features @ Wf + bf  (MFMA; fp32 result, row-major [row][f]) ----
// grid 96, block 128 (2 waves x 16 rows)  -- thrice harness-proven, verbatim
__global__ __launch_bounds__(128) void nf_kernel(const void* __restrict__ features,
                                                 const bf16_t* __restrict__ wft,
                                                 const void* __restrict__ bfv,
                                                 const int* __restrict__ flag,
                                                 float* __restrict__ nf) {
  const bool bfm = *flag != 0;
  const int t = threadIdx.x, wave = t >> 6, lane = t & 63;
  const int n16 = lane & 15, q = lane >> 4;
  const int rbase = blockIdx.x * 32 + wave * 16;
  const int arow = rbase + n16;

  f32x4 acc[8];
#pragma unroll
  for (int nt = 0; nt < 8; ++nt)
#pragma unroll
    for (int r = 0; r < 4; ++r) acc[nt][r] = 0.f;

  if (bfm) {
    const bf16_t* fp = (const bf16_t*)features + (size_t)arow * kH;
#pragma unroll
    for (int ks = 0; ks < 4; ++ks) {
      bf16x8 afr = *(const bf16x8*)(fp + ks * 32 + q * 8);
#pragma unroll
      for (int nt = 0; nt < 8; ++nt) {
        bf16x8 bfr = *(const bf16x8*)(wft + (nt * 16 + n16) * kH + ks * 32 + q * 8);
        acc[nt] = __builtin_amdgcn_mfma_f32_16x16x32_bf16(afr, bfr, acc[nt], 0, 0, 0);
      }
    }
  } else {
    const float* fp = (const float*)features + (size_t)arow * kH;
#pragma unroll
    for (int ks = 0; ks < 4; ++ks) {
      f32x4 x0 = *(const f32x4*)(fp + ks * 32 + q * 8);
      f32x4 x1 = *(const f32x4*)(fp + ks * 32 + q * 8 + 4);
      bf16x8 ahi, alo;
#pragma unroll
      for (int e = 0; e < 4; ++e) {
        bf16_t h0 = (bf16_t)x0[e]; ahi[e]     = h0; alo[e]     = (bf16_t)(x0[e] - (float)h0);
        bf16_t h1 = (bf16_t)x1[e]; ahi[e + 4] = h1; alo[e + 4] = (bf16_t)(x1[e] - (float)h1);
      }
#pragma unroll
      for (int nt = 0; nt < 8; ++nt) {
        bf16x8 bfr = *(const bf16x8*)(wft + (nt * 16 + n16) * kH + ks * 32 + q * 8);
        acc[nt] = __builtin_amdgcn_mfma_f32_16x16x32_bf16(ahi, bfr, acc[nt], 0, 0, 0);
        acc[nt] = __builtin_amdgcn_mfma_f32_16x16x32_bf16(alo, bfr, acc[nt], 0, 0, 0);
      }
    }
  }
  // C layout: col = lane&15, row = q*4 + r
#pragma unroll
  for (int nt = 0; nt < 8; ++nt) {
    const int col = nt * 16 + n16;
    const float bv = ldf(bfv, col, bfm);
#pragma unroll
    for (int r = 0; r < 4; ++r)
      nf[(size_t)(rbase + q * 4 + r) * kF + col] = acc[nt][r] + bv;
  }
}

// ---- A-fragment loader (v2/v5/v6-proven predicated dword form) ----
__device__ __forceinline__ void load_a(const void* __restrict__ rbf, bool bfm,
                                       int bi, int jrow, bf16x8& a0, bf16x8& a1) {
  if (bfm) {
    const unsigned int* rp = (const unsigned int*)rbf + (size_t)bi * 4800 + jrow * 25;
    uintx4 u0, u1;
#pragma unroll
    for (int i = 0; i < 4; ++i) u0[i] = rp[((threadIdx.x & 63) >> 4) * 4 + i];
#pragma unroll
    for (int i = 0; i < 4; ++i) {
      const int d = 16 + ((threadIdx.x & 63) >> 4) * 4 + i;
      u1[i] = (d < 25) ? rp[d] : 0u;
    }
    a0 = __builtin_bit_cast(bf16x8, u0);
    a1 = __builtin_bit_cast(bf16x8, u1);
  } else {
    const int q = (threadIdx.x & 63) >> 4;
    const float* rp = (const float*)rbf + (size_t)bi * (kN * kG) + (size_t)jrow * kG;
#pragma unroll
    for (int i = 0; i < 8; ++i) a0[i] = (bf16_t)rp[q * 8 + i];     // k<=31<50
#pragma unroll
    for (int i = 0; i < 8; ++i) {
      const int k1 = 32 + q * 8 + i;
      a1[i] = (bf16_t)((k1 < kG) ? rp[k1] : 0.f);
    }
  }
}

// ---- main: per (b,i); wave loops 3 thirds with unroll(1) + prefetch ----
__global__ __launch_bounds__(256, 4) void main_kernel(
    const void* __restrict__ rbf, const int* __restrict__ nmask,
    const void* __restrict__ b1p, const void* __restrict__ b2p,
    const bf16_t* __restrict__ w1t, const bf16_t* __restrict__ w2t,
    const float* __restrict__ nf, const int* __restrict__ flag,
    float* __restrict__ agg) {
  __shared__ __attribute__((aligned(16))) bf16_t s_t[4][16 * 128];   // 16384 B, per-wave, XOR swz
  __shared__ float s_red[4][kF];                                     // 2048 B

  const bool bfm = *flag != 0;
  const int bi = blockIdx.x;
  const int b  = bi / kN;
  const int t  = threadIdx.x;
  const int wv = t >> 6, lane = t & 63;
  const int n16 = lane & 15, q = lane >> 4;

  float b1r[8], b2r[8];
#pragma unroll
  for (int nt = 0; nt < 8; ++nt) {
    b1r[nt] = ldf(b1p, nt * 16 + n16, bfm);
    b2r[nt] = ldf(b2p, nt * 16 + n16, bfm);
  }

  float racc[8];
#pragma unroll
  for (int nt = 0; nt < 8; ++nt) racc[nt] = 0.f;

  char* tb = (char*)(s_t[wv]);
  const int swA = (n16 & 7) << 4;
  const float* nfb = nf + (size_t)b * kN * kF;

  // prefetch third 0
  bf16x8 a0, a1;
  load_a(rbf, bfm, bi, wv * 16 + n16, a0, a1);

#pragma clang loop unroll(disable)
  for (int third = 0; third < 3; ++third) {
    __builtin_amdgcn_sched_barrier(0);   // no cross-iteration scheduling (v5's 164-VGPR trap)

    // --- GEMM1: rbf-tile @ W1 (w1t zero-padded k 50..63) ---
    f32x4 acc1[8];
#pragma unroll
    for (int nt = 0; nt < 8; ++nt)
#pragma unroll
      for (int r = 0; r < 4; ++r) acc1[nt][r] = 0.f;
#pragma unroll
    for (int nt = 0; nt < 8; ++nt) {
      bf16x8 bf0 = *(const bf16x8*)(w1t + (nt * 16 + n16) * 64 + q * 8);
      acc1[nt] = __builtin_amdgcn_mfma_f32_16x16x32_bf16(a0, bf0, acc1[nt], 0, 0, 0);
    }
#pragma unroll
    for (int nt = 0; nt < 8; ++nt) {
      bf16x8 bf1 = *(const bf16x8*)(w1t + (nt * 16 + n16) * 64 + 32 + q * 8);
      acc1[nt] = __builtin_amdgcn_mfma_f32_16x16x32_bf16(a1, bf1, acc1[nt], 0, 0, 0);
    }

    // --- prefetch next third's A (hides under softplus + GEMM2) ---
    bf16x8 a0n, a1n;
    if (third < 2)
      load_a(rbf, bfm, bi, (third + 1) * 64 + wv * 16 + n16, a0n, a1n);

    // --- bias + softplus -> per-wave transpose buffer (C: col=lane&15, row=q*4+r) ---
#pragma unroll
    for (int nt = 0; nt < 8; ++nt) {
      const int colb = (nt * 16 + n16) * 2;
#pragma unroll
      for (int r = 0; r < 4; ++r) {
        const int row = q * 4 + r;
        *(bf16_t*)(tb + ((row * 256 + colb) ^ ((row & 7) << 4))) =
            (bf16_t)softplus_f(acc1[nt][r] + b1r[nt]);
      }
    }

    // --- GEMM2: Hs tile (per-wave LDS) @ W2 ---
    f32x4 c2[8];
#pragma unroll
    for (int nt = 0; nt < 8; ++nt)
#pragma unroll
      for (int r = 0; r < 4; ++r) c2[nt][r] = 0.f;
#pragma unroll
    for (int ks = 0; ks < 4; ++ks) {
      bf16x8 af = *(const bf16x8*)(tb + ((n16 * 256 + ks * 64 + q * 16) ^ swA));
#pragma unroll
      for (int nt = 0; nt < 8; ++nt) {
        bf16x8 bfr = *(const bf16x8*)(w2t + (nt * 16 + n16) * 128 + ks * 32 + q * 8);
        c2[nt] = __builtin_amdgcn_mfma_f32_16x16x32_bf16(af, bfr, c2[nt], 0, 0, 0);
      }
    }

    // --- epilogue: racc[f] += sum_r mask[j]*(FW+b2)*nf[j][f], j = jb..jb+3 ---
    const int jb = third * 64 + wv * 16 + q * 4;
    const int4 mv4 = *(const int4*)(nmask + (size_t)bi * kN + jb);   // 16B aligned
    const int* mvp = (const int*)&mv4;
#pragma unroll
    for (int nt = 0; nt < 8; ++nt) {
      const int f = nt * 16 + n16;
      float p = 0.f;
#pragma unroll
      for (int r = 0; r < 4; ++r) {
        const int j = jb + r;
        p = fmaf((float)mvp[r] * (c2[nt][r] + b2r[nt]), nfb[(size_t)j * kF + f], p);
      }
      racc[nt] += p;
    }

    a0 = a0n; a1 = a1n;
  }

  // --- reduction: over q via shuffles, over waves via LDS ---
#pragma unroll
  for (int nt = 0; nt < 8; ++nt) {
    racc[nt] += __shfl_xor(racc[nt], 16);
    racc[nt] += __shfl_xor(racc[nt], 32);
  }
  if (lane < 16) {
#pragma unroll
    for (int nt = 0; nt < 8; ++nt) s_red[wv][nt * 16 + lane] = racc[nt];
  }
  __syncthreads();
  if (t < kF)
    agg[(size_t)bi * kF + t] = s_red[0][t] + s_red[1][t] + s_red[2][t] + s_red[3][t];
}

// ---- out = features + softplus(agg@Wo1+bo1)@Wo2+bo2  (MFMA, hi/lo-split agg) ----
// grid 96, block 128  -- thrice harness-proven, verbatim
__global__ __launch_bounds__(128) void out_kernel(
    const float* __restrict__ agg, const void* __restrict__ features,
    const bf16_t* __restrict__ wo1t, const bf16_t* __restrict__ wo2t,
    const void* __restrict__ bo1, const void* __restrict__ bo2,
    const int* __restrict__ flag, void* __restrict__ out) {
  __shared__ bf16_t s_t[32 * kOutPitch];   // 8704 B
  const bool bfm = *flag != 0;
  const int t = threadIdx.x, wave = t >> 6, lane = t & 63;
  const int n16 = lane & 15, q = lane >> 4;
  const int rb = blockIdx.x * 32 + wave * 16;

  f32x4 acc[8];
#pragma unroll
  for (int nt = 0; nt < 8; ++nt)
#pragma unroll
    for (int r = 0; r < 4; ++r) acc[nt][r] = 0.f;

  const float* ap = agg + (size_t)(rb + n16) * kF;
#pragma unroll
  for (int ks = 0; ks < 4; ++ks) {
    f32x4 x0 = *(const f32x4*)(ap + ks * 32 + q * 8);
    f32x4 x1 = *(const f32x4*)(ap + ks * 32 + q * 8 + 4);
    bf16x8 ahi, alo;
#pragma unroll
    for (int e = 0; e < 4; ++e) {
      bf16_t h0 = (bf16_t)x0[e]; ahi[e]     = h0; alo[e]     = (bf16_t)(x0[e] - (float)h0);
      bf16_t h1 = (bf16_t)x1[e]; ahi[e + 4] = h1; alo[e + 4] = (bf16_t)(x1[e] - (float)h1);
    }
#pragma unroll
    for (int nt = 0; nt < 8; ++nt) {
      bf16x8 bfr = *(const bf16x8*)(wo1t + (nt * 16 + n16) * kF + ks * 32 + q * 8);
      acc[nt] = __builtin_amdgcn_mfma_f32_16x16x32_bf16(ahi, bfr, acc[nt], 0, 0, 0);
      acc[nt] = __builtin_amdgcn_mfma_f32_16x16x32_bf16(alo, bfr, acc[nt], 0, 0, 0);
    }
  }
#pragma unroll
  for (int nt = 0; nt < 8; ++nt) {
    const int col = nt * 16 + n16;
    const float bv = ldf(bo1, col, bfm);
#pragma unroll
    for (int r = 0; r < 4; ++r)
      s_t[(wave * 16 + q * 4 + r) * kOutPitch + col] = (bf16_t)softplus_f(acc[nt][r] + bv);
  }
  __syncthreads();

#pragma unroll
  for (int nt = 0; nt < 8; ++nt)
#pragma unroll
    for (int r = 0; r < 4; ++r) acc[nt][r] = 0.f;
#pragma unroll
  for (int ks = 0; ks < 4; ++ks) {
    bf16x8 afr = *(const bf16x8*)(s_t + (wave * 16 + n16) * kOutPitch + ks * 32 + q * 8);
#pragma unroll
    for (int nt = 0; nt < 8; ++nt) {
      bf16x8 bfr = *(const bf16x8*)(wo2t + (nt * 16 + n16) * kH + ks * 32 + q * 8);
      acc[nt] = __builtin_amdgcn_mfma_f32_16x16x32_bf16(afr, bfr, acc[nt], 0, 0, 0);
    }
  }
#pragma unroll
  for (int nt = 0; nt < 8; ++nt) {
    const int col = nt * 16 + n16;
    const float bv = ldf(bo2, col, bfm);
#pragma unroll
    for (int r = 0; r < 4; ++r) {
      const int row = rb + q * 4 + r;
      float res = ldf(features, (size_t)row * kH + col, bfm) + acc[nt][r] + bv;
      if (bfm) ((bf16_t*)out)[(size_t)row * kH + col] = (bf16_t)res;
      else     ((float*)out)[(size_t)row * kH + col]  = res;
    }
  }
}

extern "C" void kernel_launch(void* const* d_in, const int* in_sizes, int n_in,
                              void* d_out, int out_size, void* d_ws, size_t ws_size,
                              hipStream_t stream) {
  const void* features = d_in[0];
  const void* rbf      = d_in[1];
  const int*  nmask    = (const int*)d_in[2];
  const void* W1  = d_in[3];
  const void* b1  = d_in[4];
  const void* W2  = d_in[5];
  const void* b2  = d_in[6];
  const void* Wf  = d_in[7];
  const void* bfv = d_in[8];
  const void* Wo1 = d_in[9];
  const void* bo1 = d_in[10];
  const void* Wo2 = d_in[11];
  const void* bo2 = d_in[12];

  char* ws = (char*)d_ws;
  float*  nf   = (float*)ws;                   // 3072*128 f32 = 1,572,864 B
  float*  agg  = (float*)(ws + 1572864);       // 1,572,864 B
  bf16_t* w1t  = (bf16_t*)(ws + 3145728);      // 128*64  bf16 = 16,384 B
  bf16_t* w2t  = (bf16_t*)(ws + 3162112);      // 128*128 bf16 = 32,768 B
  bf16_t* wft  = (bf16_t*)(ws + 3194880);      // 32,768 B
  bf16_t* wo1t = (bf16_t*)(ws + 3227648);      // 32,768 B
  bf16_t* wo2t = (bf16_t*)(ws + 3260416);      // 32,768 B
  int*    flag = (int*)(ws + 3293184);         // 4 B

  detect_kernel<<<1, 256, 0, stream>>>((const unsigned int*)rbf, flag);
  prep_kernel<<<288, 256, 0, stream>>>(W1, W2, Wf, Wo1, Wo2, flag, w1t, w2t, wft, wo1t, wo2t);
  nf_kernel<<<96, 128, 0, stream>>>(features, wft, bfv, flag, nf);
  main_kernel<<<kRows, 256, 0, stream>>>(rbf, nmask, b1, b2, w1t, w2t, nf, flag, agg);
  out_kernel<<<96, 128, 0, stream>>>(agg, features, wo1t, wo2t, bo1, bo2, flag, d_out);
}

// Round 7
// 722.175 us; speedup vs baseline: 1.1425x; 1.1425x over previous
//
#include <hip/hip_runtime.h>
#include <hip/hip_bf16.h>

// InteractionBlock: B=16,N=192,H=128,F=128,G=50
//   fw  = softplus(rbf@W1+b1)@W2+b2          [B,N,N,F]   (never materialized)
//   nf  = features@Wf+bf                      [B,N,F]
//   agg = sum_j mask[b,i,j]*fw[b,i,j,:]*nf[b,j,:]
//   out = features + softplus(agg@Wo1+bo1)@Wo2+bo2
//
// v8 = v6's proven per-tile body + v1's amortization, via RUNTIME-OPAQUE
// trip count (the robust anti-unroll mechanism).
//  - v5 lesson: constant trip-3 loop fully unrolls -> 164 VGPR -> 2 waves/SIMD.
//  - v7 lesson: sched_barrier(0)+unroll(disable) -> allocator spills 671MB.
//  - Fix: NT=3 read from workspace (detect_kernel writes it); compiler cannot
//    unroll unknown-trip loop -> single-iteration footprint (~80 VGPR) ->
//    4 waves/SIMD, 4 blocks/CU resident, 12 tiles/block amortization.
//  - A-prefetch: next iteration's fragments loaded into the SAME a0/a1 regs
//    right after GEMM1's MFMAs consume them (branchless clamped index) ->
//    HBM latency hides under softplus+GEMM2+epilogue.
//  - Zero barriers inside the loop (per-wave private tb; same-wave DS ops
//    are program-ordered). Final shuffle+LDS reduction, direct store.
//  - detect/prep/nf/out kernels: proven verbatim.

typedef __bf16 bf16_t;
typedef __bf16 bf16x8 __attribute__((ext_vector_type(8)));
typedef float  f32x4  __attribute__((ext_vector_type(4)));
typedef unsigned int uintx4 __attribute__((ext_vector_type(4)));

constexpr int kB = 16, kN = 192, kH = 128, kF = 128, kG = 50;
constexpr int kRows = kB * kN;        // 3072
constexpr int kOutPitch = 136;        // bf16 elems, mult of 8 -> aligned b128

__device__ __forceinline__ float ldf(const void* p, int i, bool bfm) {
  return bfm ? (float)((const bf16_t*)p)[i] : ((const float*)p)[i];
}

__device__ __forceinline__ float softplus_f(float x) {
  float t = __logf(1.f + __expf(fminf(x, 20.f)));
  return x > 20.f ? x : t;
}

// ---- dtype detector: flag[0]=1 if packed bf16 else 0; flag[1]=3 (opaque trip) ----
__global__ __launch_bounds__(256) void detect_kernel(const unsigned int* __restrict__ rbf_w,
                                                     int* __restrict__ flag) {
  __shared__ int c_hi, c_zero;
  const int t = threadIdx.x;
  if (t == 0) { c_hi = 0; c_zero = 0; }
  __syncthreads();
  unsigned int w = rbf_w[(size_t)t * 40003u];   // in-bounds for both dtypes
  unsigned int lo = w & 0xFFFFu;
  if (((lo >> 7) & 0xFFu) >= 128u) atomicAdd(&c_hi, 1);   // |bf16| >= 2: impossible for rbf in [0,1)
  if (lo == 0u) atomicAdd(&c_zero, 1);
  __syncthreads();
  if (t == 0) {
    flag[0] = (c_hi == 0 && c_zero < 200) ? 1 : 0;
    flag[1] = 3;    // runtime-opaque trip count for main_kernel's tile loop
  }
}

// ---- transpose all weight matrices into bf16 [n][k] ----
__global__ __launch_bounds__(256) void prep_kernel(
    const void* __restrict__ W1, const void* __restrict__ W2,
    const void* __restrict__ Wf, const void* __restrict__ Wo1,
    const void* __restrict__ Wo2, const int* __restrict__ flag,
    bf16_t* __restrict__ w1t, bf16_t* __restrict__ w2t,
    bf16_t* __restrict__ wft, bf16_t* __restrict__ wo1t,
    bf16_t* __restrict__ wo2t) {
  const bool bfm = flag[0] != 0;
  int idx = blockIdx.x * 256 + threadIdx.x;
  if (idx < 8192) {                       // w1t [128][64], G padded 50->64 with zeros
    int n = idx >> 6, k = idx & 63;
    w1t[idx] = (k < kG) ? (bf16_t)ldf(W1, k * kF + n, bfm) : (bf16_t)0.f;
  } else if (idx < 8192 + 16384) {        // w2t [128][128]
    int i2 = idx - 8192; int n = i2 >> 7, k = i2 & 127;
    w2t[i2] = (bf16_t)ldf(W2, k * kF + n, bfm);
  } else if (idx < 8192 + 2 * 16384) {    // wft
    int i2 = idx - 8192 - 16384; int n = i2 >> 7, k = i2 & 127;
    wft[i2] = (bf16_t)ldf(Wf, k * kF + n, bfm);
  } else if (idx < 8192 + 3 * 16384) {    // wo1t
    int i2 = idx - 8192 - 2 * 16384; int n = i2 >> 7, k = i2 & 127;
    wo1t[i2] = (bf16_t)ldf(Wo1, k * kH + n, bfm);
  } else if (idx < 8192 + 4 * 16384) {    // wo2t
    int i2 = idx - 8192 - 3 * 16384; int n = i2 >> 7, k = i2 & 127;
    wo2t[i2] = (bf16_t)ldf(Wo2, k * kH + n, bfm);
  }
}

// ---- nf = features @ Wf + bf  (MFMA; fp32 result, row-major [row][f]) ----
// grid 96, block 128 (2 waves x 16 rows)  -- harness-proven, verbatim
__global__ __launch_bounds__(128) void nf_kernel(const void* __restrict__ features,
                                                 const bf16_t* __restrict__ wft,
                                                 const void* __restrict__ bfv,
                                                 const int* __restrict__ flag,
                                                 float* __restrict__ nf) {
  const bool bfm = flag[0] != 0;
  const int t = threadIdx.x, wave = t >> 6, lane = t & 63;
  const int n16 = lane & 15, q = lane >> 4;
  const int rbase = blockIdx.x * 32 + wave * 16;
  const int arow = rbase + n16;

  f32x4 acc[8];
#pragma unroll
  for (int nt = 0; nt < 8; ++nt)
#pragma unroll
    for (int r = 0; r < 4; ++r) acc[nt][r] = 0.f;

  if (bfm) {
    const bf16_t* fp = (const bf16_t*)features + (size_t)arow * kH;
#pragma unroll
    for (int ks = 0; ks < 4; ++ks) {
      bf16x8 afr = *(const bf16x8*)(fp + ks * 32 + q * 8);
#pragma unroll
      for (int nt = 0; nt < 8; ++nt) {
        bf16x8 bfr = *(const bf16x8*)(wft + (nt * 16 + n16) * kH + ks * 32 + q * 8);
        acc[nt] = __builtin_amdgcn_mfma_f32_16x16x32_bf16(afr, bfr, acc[nt], 0, 0, 0);
      }
    }
  } else {
    const float* fp = (const float*)features + (size_t)arow * kH;
#pragma unroll
    for (int ks = 0; ks < 4; ++ks) {
      f32x4 x0 = *(const f32x4*)(fp + ks * 32 + q * 8);
      f32x4 x1 = *(const f32x4*)(fp + ks * 32 + q * 8 + 4);
      bf16x8 ahi, alo;
#pragma unroll
      for (int e = 0; e < 4; ++e) {
        bf16_t h0 = (bf16_t)x0[e]; ahi[e]     = h0; alo[e]     = (bf16_t)(x0[e] - (float)h0);
        bf16_t h1 = (bf16_t)x1[e]; ahi[e + 4] = h1; alo[e + 4] = (bf16_t)(x1[e] - (float)h1);
      }
#pragma unroll
      for (int nt = 0; nt < 8; ++nt) {
        bf16x8 bfr = *(const bf16x8*)(wft + (nt * 16 + n16) * kH + ks * 32 + q * 8);
        acc[nt] = __builtin_amdgcn_mfma_f32_16x16x32_bf16(ahi, bfr, acc[nt], 0, 0, 0);
        acc[nt] = __builtin_amdgcn_mfma_f32_16x16x32_bf16(alo, bfr, acc[nt], 0, 0, 0);
      }
    }
  }
  // C layout: col = lane&15, row = q*4 + r
#pragma unroll
  for (int nt = 0; nt < 8; ++nt) {
    const int col = nt * 16 + n16;
    const float bv = ldf(bfv, col, bfm);
#pragma unroll
    for (int r = 0; r < 4; ++r)
      nf[(size_t)(rbase + q * 4 + r) * kF + col] = acc[nt][r] + bv;
  }
}

// ---- A-fragment loader (v2/v5/v6-proven predicated dword form) ----
__device__ __forceinline__ void load_a(const void* __restrict__ rbf, bool bfm,
                                       int bi, int jrow, bf16x8& a0, bf16x8& a1) {
  const int q = (threadIdx.x & 63) >> 4;
  if (bfm) {
    const unsigned int* rp = (const unsigned int*)rbf + (size_t)bi * 4800 + jrow * 25;
    uintx4 u0, u1;
#pragma unroll
    for (int i = 0; i < 4; ++i) u0[i] = rp[q * 4 + i];             // k 0..31: always valid
#pragma unroll
    for (int i = 0; i < 4; ++i) {
      const int d = 16 + q * 4 + i;                                // k 32..63: predicate d<25
      u1[i] = (d < 25) ? rp[d] : 0u;
    }
    a0 = __builtin_bit_cast(bf16x8, u0);
    a1 = __builtin_bit_cast(bf16x8, u1);
  } else {
    const float* rp = (const float*)rbf + (size_t)bi * (kN * kG) + (size_t)jrow * kG;
#pragma unroll
    for (int i = 0; i < 8; ++i) a0[i] = (bf16_t)rp[q * 8 + i];     // k<=31<50
#pragma unroll
    for (int i = 0; i < 8; ++i) {
      const int k1 = 32 + q * 8 + i;
      a1[i] = (bf16_t)((k1 < kG) ? rp[k1] : 0.f);
    }
  }
}

// ---- main: per (b,i); wave loops NT(=3, runtime-opaque) tiles; no barriers ----
__global__ __launch_bounds__(256, 4) void main_kernel(
    const void* __restrict__ rbf, const int* __restrict__ nmask,
    const void* __restrict__ b1p, const void* __restrict__ b2p,
    const bf16_t* __restrict__ w1t, const bf16_t* __restrict__ w2t,
    const float* __restrict__ nf, const int* __restrict__ flag,
    float* __restrict__ agg) {
  __shared__ __attribute__((aligned(16))) bf16_t s_t[4][16 * 128];   // 16384 B, per-wave, XOR swz
  __shared__ float s_red[4][kF];                                     // 2048 B

  const bool bfm = flag[0] != 0;
  const int  NT  = flag[1];                  // ==3, but compiler can't know -> loop stays rolled
  const int bi = blockIdx.x;
  const int b  = bi / kN;
  const int t  = threadIdx.x;
  const int wv = t >> 6, lane = t & 63;
  const int n16 = lane & 15, q = lane >> 4;

  float b1r[8], b2r[8];
#pragma unroll
  for (int nt = 0; nt < 8; ++nt) {
    b1r[nt] = ldf(b1p, nt * 16 + n16, bfm);
    b2r[nt] = ldf(b2p, nt * 16 + n16, bfm);
  }

  float racc[8];
#pragma unroll
  for (int nt = 0; nt < 8; ++nt) racc[nt] = 0.f;

  char* tb = (char*)(s_t[wv]);
  const int swA = (n16 & 7) << 4;
  const float* nfb = nf + (size_t)b * kN * kF;

  // prefetch tile 0's A-fragments
  bf16x8 a0, a1;
  load_a(rbf, bfm, bi, wv * 16 + n16, a0, a1);

  for (int third = 0; third < NT; ++third) {
    // --- GEMM1: rbf-tile @ W1 (w1t zero-padded k 50..63) ---
    f32x4 acc1[8];
#pragma unroll
    for (int nt = 0; nt < 8; ++nt)
#pragma unroll
      for (int r = 0; r < 4; ++r) acc1[nt][r] = 0.f;
#pragma unroll
    for (int nt = 0; nt < 8; ++nt) {
      bf16x8 bf0 = *(const bf16x8*)(w1t + (nt * 16 + n16) * 64 + q * 8);
      acc1[nt] = __builtin_amdgcn_mfma_f32_16x16x32_bf16(a0, bf0, acc1[nt], 0, 0, 0);
    }
#pragma unroll
    for (int nt = 0; nt < 8; ++nt) {
      bf16x8 bf1 = *(const bf16x8*)(w1t + (nt * 16 + n16) * 64 + 32 + q * 8);
      acc1[nt] = __builtin_amdgcn_mfma_f32_16x16x32_bf16(a1, bf1, acc1[nt], 0, 0, 0);
    }

    // --- prefetch next tile's A into the SAME regs (a0/a1 now dead) ---
    {
      const int nxt = (third + 1 < NT) ? (third + 1) : third;   // clamped, branchless
      load_a(rbf, bfm, bi, nxt * 64 + wv * 16 + n16, a0, a1);
    }

    // --- bias + softplus -> per-wave transpose buffer (C: col=lane&15, row=q*4+r) ---
#pragma unroll
    for (int nt = 0; nt < 8; ++nt) {
      const int colb = (nt * 16 + n16) * 2;
#pragma unroll
      for (int r = 0; r < 4; ++r) {
        const int row = q * 4 + r;
        *(bf16_t*)(tb + ((row * 256 + colb) ^ ((row & 7) << 4))) =
            (bf16_t)softplus_f(acc1[nt][r] + b1r[nt]);
      }
    }

    // --- GEMM2: Hs tile (per-wave LDS) @ W2 ---
    f32x4 c2[8];
#pragma unroll
    for (int nt = 0; nt < 8; ++nt)
#pragma unroll
      for (int r = 0; r < 4; ++r) c2[nt][r] = 0.f;
#pragma unroll
    for (int ks = 0; ks < 4; ++ks) {
      bf16x8 af = *(const bf16x8*)(tb + ((n16 * 256 + ks * 64 + q * 16) ^ swA));
#pragma unroll
      for (int nt = 0; nt < 8; ++nt) {
        bf16x8 bfr = *(const bf16x8*)(w2t + (nt * 16 + n16) * 128 + ks * 32 + q * 8);
        c2[nt] = __builtin_amdgcn_mfma_f32_16x16x32_bf16(af, bfr, c2[nt], 0, 0, 0);
      }
    }

    // --- epilogue: racc[f] += sum_r mask[j]*(FW+b2)*nf[j][f], j = jb..jb+3 ---
    const int jb = third * 64 + wv * 16 + q * 4;
    const int4 mv4 = *(const int4*)(nmask + (size_t)bi * kN + jb);   // 16B aligned
    const int* mvp = (const int*)&mv4;
#pragma unroll
    for (int nt = 0; nt < 8; ++nt) {
      const int f = nt * 16 + n16;
      float p = 0.f;
#pragma unroll
      for (int r = 0; r < 4; ++r) {
        const int j = jb + r;
        p = fmaf((float)mvp[r] * (c2[nt][r] + b2r[nt]), nfb[(size_t)j * kF + f], p);
      }
      racc[nt] += p;
    }
  }

  // --- reduction: over q via shuffles, over waves via LDS ---
#pragma unroll
  for (int nt = 0; nt < 8; ++nt) {
    racc[nt] += __shfl_xor(racc[nt], 16);
    racc[nt] += __shfl_xor(racc[nt], 32);
  }
  if (lane < 16) {
#pragma unroll
    for (int nt = 0; nt < 8; ++nt) s_red[wv][nt * 16 + lane] = racc[nt];
  }
  __syncthreads();
  if (t < kF)
    agg[(size_t)bi * kF + t] = s_red[0][t] + s_red[1][t] + s_red[2][t] + s_red[3][t];
}

// ---- out = features + softplus(agg@Wo1+bo1)@Wo2+bo2  (MFMA, hi/lo-split agg) ----
// grid 96, block 128  -- harness-proven, verbatim
__global__ __launch_bounds__(128) void out_kernel(
    const float* __restrict__ agg, const void* __restrict__ features,
    const bf16_t* __restrict__ wo1t, const bf16_t* __restrict__ wo2t,
    const void* __restrict__ bo1, const void* __restrict__ bo2,
    const int* __restrict__ flag, void* __restrict__ out) {
  __shared__ bf16_t s_t[32 * kOutPitch];   // 8704 B
  const bool bfm = flag[0] != 0;
  const int t = threadIdx.x, wave = t >> 6, lane = t & 63;
  const int n16 = lane & 15, q = lane >> 4;
  const int rb = blockIdx.x * 32 + wave * 16;

  f32x4 acc[8];
#pragma unroll
  for (int nt = 0; nt < 8; ++nt)
#pragma unroll
    for (int r = 0; r < 4; ++r) acc[nt][r] = 0.f;

  const float* ap = agg + (size_t)(rb + n16) * kF;
#pragma unroll
  for (int ks = 0; ks < 4; ++ks) {
    f32x4 x0 = *(const f32x4*)(ap + ks * 32 + q * 8);
    f32x4 x1 = *(const f32x4*)(ap + ks * 32 + q * 8 + 4);
    bf16x8 ahi, alo;
#pragma unroll
    for (int e = 0; e < 4; ++e) {
      bf16_t h0 = (bf16_t)x0[e]; ahi[e]     = h0; alo[e]     = (bf16_t)(x0[e] - (float)h0);
      bf16_t h1 = (bf16_t)x1[e]; ahi[e + 4] = h1; alo[e + 4] = (bf16_t)(x1[e] - (float)h1);
    }
#pragma unroll
    for (int nt = 0; nt < 8; ++nt) {
      bf16x8 bfr = *(const bf16x8*)(wo1t + (nt * 16 + n16) * kF + ks * 32 + q * 8);
      acc[nt] = __builtin_amdgcn_mfma_f32_16x16x32_bf16(ahi, bfr, acc[nt], 0, 0, 0);
      acc[nt] = __builtin_amdgcn_mfma_f32_16x16x32_bf16(alo, bfr, acc[nt], 0, 0, 0);
    }
  }
#pragma unroll
  for (int nt = 0; nt < 8; ++nt) {
    const int col = nt * 16 + n16;
    const float bv = ldf(bo1, col, bfm);
#pragma unroll
    for (int r = 0; r < 4; ++r)
      s_t[(wave * 16 + q * 4 + r) * kOutPitch + col] = (bf16_t)softplus_f(acc[nt][r] + bv);
  }
  __syncthreads();

#pragma unroll
  for (int nt = 0; nt < 8; ++nt)
#pragma unroll
    for (int r = 0; r < 4; ++r) acc[nt][r] = 0.f;
#pragma unroll
  for (int ks = 0; ks < 4; ++ks) {
    bf16x8 afr = *(const bf16x8*)(s_t + (wave * 16 + n16) * kOutPitch + ks * 32 + q * 8);
#pragma unroll
    for (int nt = 0; nt < 8; ++nt) {
      bf16x8 bfr = *(const bf16x8*)(wo2t + (nt * 16 + n16) * kH + ks * 32 + q * 8);
      acc[nt] = __builtin_amdgcn_mfma_f32_16x16x32_bf16(afr, bfr, acc[nt], 0, 0, 0);
    }
  }
#pragma unroll
  for (int nt = 0; nt < 8; ++nt) {
    const int col = nt * 16 + n16;
    const float bv = ldf(bo2, col, bfm);
#pragma unroll
    for (int r = 0; r < 4; ++r) {
      const int row = rb + q * 4 + r;
      float res = ldf(features, (size_t)row * kH + col, bfm) + acc[nt][r] + bv;
      if (bfm) ((bf16_t*)out)[(size_t)row * kH + col] = (bf16_t)res;
      else     ((float*)out)[(size_t)row * kH + col]  = res;
    }
  }
}

extern "C" void kernel_launch(void* const* d_in, const int* in_sizes, int n_in,
                              void* d_out, int out_size, void* d_ws, size_t ws_size,
                              hipStream_t stream) {
  const void* features = d_in[0];
  const void* rbf      = d_in[1];
  const int*  nmask    = (const int*)d_in[2];
  const void* W1  = d_in[3];
  const void* b1  = d_in[4];
  const void* W2  = d_in[5];
  const void* b2  = d_in[6];
  const void* Wf  = d_in[7];
  const void* bfv = d_in[8];
  const void* Wo1 = d_in[9];
  const void* bo1 = d_in[10];
  const void* Wo2 = d_in[11];
  const void* bo2 = d_in[12];

  char* ws = (char*)d_ws;
  float*  nf   = (float*)ws;                   // 3072*128 f32 = 1,572,864 B
  float*  agg  = (float*)(ws + 1572864);       // 1,572,864 B
  bf16_t* w1t  = (bf16_t*)(ws + 3145728);      // 128*64  bf16 = 16,384 B
  bf16_t* w2t  = (bf16_t*)(ws + 3162112);      // 128*128 bf16 = 32,768 B
  bf16_t* wft  = (bf16_t*)(ws + 3194880);      // 32,768 B
  bf16_t* wo1t = (bf16_t*)(ws + 3227648);      // 32,768 B
  bf16_t* wo2t = (bf16_t*)(ws + 3260416);      // 32,768 B
  int*    flag = (int*)(ws + 3293184);         // 8 B (flag[0]=dtype, flag[1]=NT)

  detect_kernel<<<1, 256, 0, stream>>>((const unsigned int*)rbf, flag);
  prep_kernel<<<288, 256, 0, stream>>>(W1, W2, Wf, Wo1, Wo2, flag, w1t, w2t, wft, wo1t, wo2t);
  nf_kernel<<<96, 128, 0, stream>>>(features, wft, bfv, flag, nf);
  main_kernel<<<kRows, 256, 0, stream>>>(rbf, nmask, b1, b2, w1t, w2t, nf, flag, agg);
  out_kernel<<<96, 128, 0, stream>>>(agg, features, wo1t, wo2t, bo1, bo2, flag, d_out);
}

// Round 8
// 402.980 us; speedup vs baseline: 2.0475x; 1.7921x over previous
//
#include <hip/hip_runtime.h>
#include <hip/hip_bf16.h>

// InteractionBlock: B=16,N=192,H=128,F=128,G=50
//   fw  = softplus(rbf@W1+b1)@W2+b2          [B,N,N,F]   (never materialized)
//   nf  = features@Wf+bf                      [B,N,F]
//   agg = sum_j mask[b,i,j]*fw[b,i,j,:]*nf[b,j,:]
//   out = features + softplus(agg@Wo1+bo1)@Wo2+bo2
//
// v9 = RETURN TO v1 (best measured main: 178us, 108 VGPR, no spills) with
// exactly two independently-proven micro-fixes. Nothing else changed.
//  - v5-v8 lessons: any loop-carried restructure of this body needs >128 regs;
//    capping spills (v7: 671MB, v8: 604MB scratch), not capping kills
//    occupancy (v5: 164 VGPR). v1's 12-tile/block straight-through structure
//    with acc[3][8] is the proven local optimum. Polish it, don't fight it.
//  - Fix 1: GEMM1 A-loads as predicated dwords (v5/v6-proven form, dense
//    rows): 12 dword loads/lane instead of 48 scalar 2B loads.
//  - Fix 2: epilogue via per-wave racc + shfl_xor(16,32) + s_red cross-wave
//    add (v3/v5/v6-proven) instead of 2048 serialized LDS atomicAdds/block.
//  - nf/out/prep: MFMA versions (v4-v8 proven). No launch-bound games.

typedef __bf16 bf16_t;
typedef __bf16 bf16x8 __attribute__((ext_vector_type(8)));
typedef float  f32x4  __attribute__((ext_vector_type(4)));
typedef unsigned int uintx4 __attribute__((ext_vector_type(4)));

constexpr int kB = 16, kN = 192, kH = 128, kF = 128, kG = 50;
constexpr int kRows = kB * kN;        // 3072
constexpr int kHsPitch = 136;         // bf16 elems; v1-proven pitch (no b128 conflict pattern)
constexpr int kOutPitch = 136;

__device__ __forceinline__ float ldf(const void* p, int i, bool bfm) {
  return bfm ? (float)((const bf16_t*)p)[i] : ((const float*)p)[i];
}

__device__ __forceinline__ float softplus_f(float x) {
  float t = __logf(1.f + __expf(fminf(x, 20.f)));
  return x > 20.f ? x : t;
}

// ---- dtype detector: flag[0]=1 if inputs are packed bf16, 0 if fp32 ----
__global__ __launch_bounds__(256) void detect_kernel(const unsigned int* __restrict__ rbf_w,
                                                     int* __restrict__ flag) {
  __shared__ int c_hi, c_zero;
  const int t = threadIdx.x;
  if (t == 0) { c_hi = 0; c_zero = 0; }
  __syncthreads();
  unsigned int w = rbf_w[(size_t)t * 40003u];   // in-bounds for both dtypes
  unsigned int lo = w & 0xFFFFu;
  if (((lo >> 7) & 0xFFu) >= 128u) atomicAdd(&c_hi, 1);   // |bf16| >= 2: impossible for rbf in [0,1)
  if (lo == 0u) atomicAdd(&c_zero, 1);
  __syncthreads();
  if (t == 0) flag[0] = (c_hi == 0 && c_zero < 200) ? 1 : 0;
}

// ---- transpose all weight matrices into bf16 [n][k] ----
__global__ __launch_bounds__(256) void prep_kernel(
    const void* __restrict__ W1, const void* __restrict__ W2,
    const void* __restrict__ Wf, const void* __restrict__ Wo1,
    const void* __restrict__ Wo2, const int* __restrict__ flag,
    bf16_t* __restrict__ w1t, bf16_t* __restrict__ w2t,
    bf16_t* __restrict__ wft, bf16_t* __restrict__ wo1t,
    bf16_t* __restrict__ wo2t) {
  const bool bfm = flag[0] != 0;
  int idx = blockIdx.x * 256 + threadIdx.x;
  if (idx < 8192) {                       // w1t [128][64], G padded 50->64 with zeros
    int n = idx >> 6, k = idx & 63;
    w1t[idx] = (k < kG) ? (bf16_t)ldf(W1, k * kF + n, bfm) : (bf16_t)0.f;
  } else if (idx < 8192 + 16384) {        // w2t [128][128]
    int i2 = idx - 8192; int n = i2 >> 7, k = i2 & 127;
    w2t[i2] = (bf16_t)ldf(W2, k * kF + n, bfm);
  } else if (idx < 8192 + 2 * 16384) {    // wft
    int i2 = idx - 8192 - 16384; int n = i2 >> 7, k = i2 & 127;
    wft[i2] = (bf16_t)ldf(Wf, k * kF + n, bfm);
  } else if (idx < 8192 + 3 * 16384) {    // wo1t
    int i2 = idx - 8192 - 2 * 16384; int n = i2 >> 7, k = i2 & 127;
    wo1t[i2] = (bf16_t)ldf(Wo1, k * kH + n, bfm);
  } else if (idx < 8192 + 4 * 16384) {    // wo2t
    int i2 = idx - 8192 - 3 * 16384; int n = i2 >> 7, k = i2 & 127;
    wo2t[i2] = (bf16_t)ldf(Wo2, k * kH + n, bfm);
  }
}

// ---- nf = features @ Wf + bf  (MFMA; fp32 result, row-major [row][f]) ----
// grid 96, block 128 (2 waves x 16 rows)  -- harness-proven, verbatim
__global__ __launch_bounds__(128) void nf_kernel(const void* __restrict__ features,
                                                 const bf16_t* __restrict__ wft,
                                                 const void* __restrict__ bfv,
                                                 const int* __restrict__ flag,
                                                 float* __restrict__ nf) {
  const bool bfm = flag[0] != 0;
  const int t = threadIdx.x, wave = t >> 6, lane = t & 63;
  const int n16 = lane & 15, q = lane >> 4;
  const int rbase = blockIdx.x * 32 + wave * 16;
  const int arow = rbase + n16;

  f32x4 acc[8];
#pragma unroll
  for (int nt = 0; nt < 8; ++nt)
#pragma unroll
    for (int r = 0; r < 4; ++r) acc[nt][r] = 0.f;

  if (bfm) {
    const bf16_t* fp = (const bf16_t*)features + (size_t)arow * kH;
#pragma unroll
    for (int ks = 0; ks < 4; ++ks) {
      bf16x8 afr = *(const bf16x8*)(fp + ks * 32 + q * 8);
#pragma unroll
      for (int nt = 0; nt < 8; ++nt) {
        bf16x8 bfr = *(const bf16x8*)(wft + (nt * 16 + n16) * kH + ks * 32 + q * 8);
        acc[nt] = __builtin_amdgcn_mfma_f32_16x16x32_bf16(afr, bfr, acc[nt], 0, 0, 0);
      }
    }
  } else {
    const float* fp = (const float*)features + (size_t)arow * kH;
#pragma unroll
    for (int ks = 0; ks < 4; ++ks) {
      f32x4 x0 = *(const f32x4*)(fp + ks * 32 + q * 8);
      f32x4 x1 = *(const f32x4*)(fp + ks * 32 + q * 8 + 4);
      bf16x8 ahi, alo;
#pragma unroll
      for (int e = 0; e < 4; ++e) {
        bf16_t h0 = (bf16_t)x0[e]; ahi[e]     = h0; alo[e]     = (bf16_t)(x0[e] - (float)h0);
        bf16_t h1 = (bf16_t)x1[e]; ahi[e + 4] = h1; alo[e + 4] = (bf16_t)(x1[e] - (float)h1);
      }
#pragma unroll
      for (int nt = 0; nt < 8; ++nt) {
        bf16x8 bfr = *(const bf16x8*)(wft + (nt * 16 + n16) * kH + ks * 32 + q * 8);
        acc[nt] = __builtin_amdgcn_mfma_f32_16x16x32_bf16(ahi, bfr, acc[nt], 0, 0, 0);
        acc[nt] = __builtin_amdgcn_mfma_f32_16x16x32_bf16(alo, bfr, acc[nt], 0, 0, 0);
      }
    }
  }
  // C layout: col = lane&15, row = q*4 + r
#pragma unroll
  for (int nt = 0; nt < 8; ++nt) {
    const int col = nt * 16 + n16;
    const float bv = ldf(bfv, col, bfm);
#pragma unroll
    for (int r = 0; r < 4; ++r)
      nf[(size_t)(rbase + q * 4 + r) * kF + col] = acc[nt][r] + bv;
  }
}

// ---- main: v1 structure. One block per (b,i); each wave owns 48 rows
// ----       (3 M-tiles). GEMM1 -> softplus -> shared s_hs -> GEMM2 ->
// ----       masked nf epilogue -> shuffle+LDS reduction (no atomics).
__global__ __launch_bounds__(256) void main_kernel(
    const void* __restrict__ rbf, const int* __restrict__ nmask,
    const void* __restrict__ b1p, const void* __restrict__ b2p,
    const bf16_t* __restrict__ w1t, const bf16_t* __restrict__ w2t,
    const float* __restrict__ nf, const int* __restrict__ flag,
    float* __restrict__ agg) {
  __shared__ bf16_t s_hs[kN * kHsPitch];   // 52224 B (v1-proven layout)
  __shared__ float  s_mask[kN];            // 768 B
  __shared__ float  s_red[4][kF];          // 2048 B

  const bool bfm = flag[0] != 0;
  const int bi = blockIdx.x;
  const int b  = bi / kN;
  const int t  = threadIdx.x;
  const int wave = t >> 6, lane = t & 63;
  const int n16 = lane & 15, q = lane >> 4;
  const int m0w = wave * 48;               // this wave's 48 rows (3 M-tiles)

  for (int idx = t; idx < kN; idx += 256) s_mask[idx] = (float)nmask[bi * kN + idx];

  f32x4 acc[3][8];
#pragma unroll
  for (int mt = 0; mt < 3; ++mt)
#pragma unroll
    for (int nt = 0; nt < 8; ++nt)
#pragma unroll
      for (int r = 0; r < 4; ++r) acc[mt][nt][r] = 0.f;

  // ---- GEMM1: H[192,128] = rbf[192, 50->64] @ W1 (dword A-loads, dense rows) ----
#pragma unroll
  for (int ks = 0; ks < 2; ++ks) {
    bf16x8 afr[3];
#pragma unroll
    for (int mt = 0; mt < 3; ++mt) {
      const int j = m0w + mt * 16 + n16;           // A[m = lane&15], dense row
      if (bfm) {
        const unsigned int* rp = (const unsigned int*)rbf + (size_t)bi * 4800 + j * 25;
        uintx4 u;
#pragma unroll
        for (int i = 0; i < 4; ++i) {
          const int d = ks * 16 + q * 4 + i;       // dword index; row = 25 dwords
          u[i] = (d < 25) ? rp[d] : 0u;            // ks=0: always true (folds)
        }
        afr[mt] = __builtin_bit_cast(bf16x8, u);
      } else {
        const float* rp = (const float*)rbf + (size_t)bi * (kN * kG) + (size_t)j * kG;
#pragma unroll
        for (int i = 0; i < 8; ++i) {
          const int k = ks * 32 + q * 8 + i;
          afr[mt][i] = (bf16_t)((k < kG) ? rp[k] : 0.f);
        }
      }
    }
#pragma unroll
    for (int nt = 0; nt < 8; ++nt) {
      bf16x8 bfr = *(const bf16x8*)(w1t + (nt * 16 + n16) * 64 + ks * 32 + q * 8);
#pragma unroll
      for (int mt = 0; mt < 3; ++mt)
        acc[mt][nt] = __builtin_amdgcn_mfma_f32_16x16x32_bf16(afr[mt], bfr, acc[mt][nt], 0, 0, 0);
    }
  }

  // bias + softplus -> s_hs (bf16). C/D layout: col = lane&15, row = q*4 + r.
#pragma unroll
  for (int nt = 0; nt < 8; ++nt) {
    const int col = nt * 16 + n16;
    const float bb = ldf(b1p, col, bfm);
#pragma unroll
    for (int mt = 0; mt < 3; ++mt) {
      const int jb = m0w + mt * 16 + q * 4;
#pragma unroll
      for (int r = 0; r < 4; ++r)
        s_hs[(jb + r) * kHsPitch + col] = (bf16_t)softplus_f(acc[mt][nt][r] + bb);
    }
  }
  __syncthreads();

  // ---- GEMM2: FW = Hs[192,128] @ W2[128,128] ----
#pragma unroll
  for (int mt = 0; mt < 3; ++mt)
#pragma unroll
    for (int nt = 0; nt < 8; ++nt)
#pragma unroll
      for (int r = 0; r < 4; ++r) acc[mt][nt][r] = 0.f;

#pragma unroll
  for (int ks = 0; ks < 4; ++ks) {
    bf16x8 afr[3];
#pragma unroll
    for (int mt = 0; mt < 3; ++mt)
      afr[mt] = *(const bf16x8*)(s_hs + (m0w + mt * 16 + n16) * kHsPitch + ks * 32 + q * 8);
#pragma unroll
    for (int nt = 0; nt < 8; ++nt) {
      bf16x8 bfr = *(const bf16x8*)(w2t + (nt * 16 + n16) * 128 + ks * 32 + q * 8);
#pragma unroll
      for (int mt = 0; mt < 3; ++mt)
        acc[mt][nt] = __builtin_amdgcn_mfma_f32_16x16x32_bf16(afr[mt], bfr, acc[mt][nt], 0, 0, 0);
    }
  }

  // ---- epilogue: racc[f] = sum over this wave's 48 rows of mask*(fw+b2)*nf ----
  const float* nfb = nf + (size_t)b * kN * kF;
  float racc[8];
#pragma unroll
  for (int nt = 0; nt < 8; ++nt) {
    const int f = nt * 16 + n16;
    const float b2v = ldf(b2p, f, bfm);
    float p = 0.f;
#pragma unroll
    for (int mt = 0; mt < 3; ++mt) {
      const int jb = m0w + mt * 16 + q * 4;
#pragma unroll
      for (int r = 0; r < 4; ++r) {
        const int j = jb + r;
        p = fmaf(s_mask[j] * (acc[mt][nt][r] + b2v), nfb[(size_t)j * kF + f], p);
      }
    }
    racc[nt] = p;
  }

  // reduction over q via shuffles, over waves via LDS (no atomics)
#pragma unroll
  for (int nt = 0; nt < 8; ++nt) {
    racc[nt] += __shfl_xor(racc[nt], 16);
    racc[nt] += __shfl_xor(racc[nt], 32);
  }
  if (lane < 16) {
#pragma unroll
    for (int nt = 0; nt < 8; ++nt) s_red[wave][nt * 16 + lane] = racc[nt];
  }
  __syncthreads();
  if (t < kF)
    agg[(size_t)bi * kF + t] = s_red[0][t] + s_red[1][t] + s_red[2][t] + s_red[3][t];
}

// ---- out = features + softplus(agg@Wo1+bo1)@Wo2+bo2  (MFMA, hi/lo-split agg) ----
// grid 96, block 128  -- harness-proven, verbatim
__global__ __launch_bounds__(128) void out_kernel(
    const float* __restrict__ agg, const void* __restrict__ features,
    const bf16_t* __restrict__ wo1t, const bf16_t* __restrict__ wo2t,
    const void* __restrict__ bo1, const void* __restrict__ bo2,
    const int* __restrict__ flag, void* __restrict__ out) {
  __shared__ bf16_t s_t[32 * kOutPitch];   // 8704 B
  const bool bfm = flag[0] != 0;
  const int t = threadIdx.x, wave = t >> 6, lane = t & 63;
  const int n16 = lane & 15, q = lane >> 4;
  const int rb = blockIdx.x * 32 + wave * 16;

  f32x4 acc[8];
#pragma unroll
  for (int nt = 0; nt < 8; ++nt)
#pragma unroll
    for (int r = 0; r < 4; ++r) acc[nt][r] = 0.f;

  const float* ap = agg + (size_t)(rb + n16) * kF;
#pragma unroll
  for (int ks = 0; ks < 4; ++ks) {
    f32x4 x0 = *(const f32x4*)(ap + ks * 32 + q * 8);
    f32x4 x1 = *(const f32x4*)(ap + ks * 32 + q * 8 + 4);
    bf16x8 ahi, alo;
#pragma unroll
    for (int e = 0; e < 4; ++e) {
      bf16_t h0 = (bf16_t)x0[e]; ahi[e]     = h0; alo[e]     = (bf16_t)(x0[e] - (float)h0);
      bf16_t h1 = (bf16_t)x1[e]; ahi[e + 4] = h1; alo[e + 4] = (bf16_t)(x1[e] - (float)h1);
    }
#pragma unroll
    for (int nt = 0; nt < 8; ++nt) {
      bf16x8 bfr = *(const bf16x8*)(wo1t + (nt * 16 + n16) * kF + ks * 32 + q * 8);
      acc[nt] = __builtin_amdgcn_mfma_f32_16x16x32_bf16(ahi, bfr, acc[nt], 0, 0, 0);
      acc[nt] = __builtin_amdgcn_mfma_f32_16x16x32_bf16(alo, bfr, acc[nt], 0, 0, 0);
    }
  }
#pragma unroll
  for (int nt = 0; nt < 8; ++nt) {
    const int col = nt * 16 + n16;
    const float bv = ldf(bo1, col, bfm);
#pragma unroll
    for (int r = 0; r < 4; ++r)
      s_t[(wave * 16 + q * 4 + r) * kOutPitch + col] = (bf16_t)softplus_f(acc[nt][r] + bv);
  }
  __syncthreads();

#pragma unroll
  for (int nt = 0; nt < 8; ++nt)
#pragma unroll
    for (int r = 0; r < 4; ++r) acc[nt][r] = 0.f;
#pragma unroll
  for (int ks = 0; ks < 4; ++ks) {
    bf16x8 afr = *(const bf16x8*)(s_t + (wave * 16 + n16) * kOutPitch + ks * 32 + q * 8);
#pragma unroll
    for (int nt = 0; nt < 8; ++nt) {
      bf16x8 bfr = *(const bf16x8*)(wo2t + (nt * 16 + n16) * kH + ks * 32 + q * 8);
      acc[nt] = __builtin_amdgcn_mfma_f32_16x16x32_bf16(afr, bfr, acc[nt], 0, 0, 0);
    }
  }
#pragma unroll
  for (int nt = 0; nt < 8; ++nt) {
    const int col = nt * 16 + n16;
    const float bv = ldf(bo2, col, bfm);
#pragma unroll
    for (int r = 0; r < 4; ++r) {
      const int row = rb + q * 4 + r;
      float res = ldf(features, (size_t)row * kH + col, bfm) + acc[nt][r] + bv;
      if (bfm) ((bf16_t*)out)[(size_t)row * kH + col] = (bf16_t)res;
      else     ((float*)out)[(size_t)row * kH + col]  = res;
    }
  }
}

extern "C" void kernel_launch(void* const* d_in, const int* in_sizes, int n_in,
                              void* d_out, int out_size, void* d_ws, size_t ws_size,
                              hipStream_t stream) {
  const void* features = d_in[0];
  const void* rbf      = d_in[1];
  const int*  nmask    = (const int*)d_in[2];
  const void* W1  = d_in[3];
  const void* b1  = d_in[4];
  const void* W2  = d_in[5];
  const void* b2  = d_in[6];
  const void* Wf  = d_in[7];
  const void* bfv = d_in[8];
  const void* Wo1 = d_in[9];
  const void* bo1 = d_in[10];
  const void* Wo2 = d_in[11];
  const void* bo2 = d_in[12];

  char* ws = (char*)d_ws;
  float*  nf   = (float*)ws;                   // 3072*128 f32 = 1,572,864 B
  float*  agg  = (float*)(ws + 1572864);       // 1,572,864 B
  bf16_t* w1t  = (bf16_t*)(ws + 3145728);      // 128*64  bf16 = 16,384 B
  bf16_t* w2t  = (bf16_t*)(ws + 3162112);      // 128*128 bf16 = 32,768 B
  bf16_t* wft  = (bf16_t*)(ws + 3194880);      // 32,768 B
  bf16_t* wo1t = (bf16_t*)(ws + 3227648);      // 32,768 B
  bf16_t* wo2t = (bf16_t*)(ws + 3260416);      // 32,768 B
  int*    flag = (int*)(ws + 3293184);         // 4 B

  detect_kernel<<<1, 256, 0, stream>>>((const unsigned int*)rbf, flag);
  prep_kernel<<<288, 256, 0, stream>>>(W1, W2, Wf, Wo1, Wo2, flag, w1t, w2t, wft, wo1t, wo2t);
  nf_kernel<<<96, 128, 0, stream>>>(features, wft, bfv, flag, nf);
  main_kernel<<<kRows, 256, 0, stream>>>(rbf, nmask, b1, b2, w1t, w2t, nf, flag, agg);
  out_kernel<<<96, 128, 0, stream>>>(agg, features, wo1t, wo2t, bo1, bo2, flag, d_out);
}